// Round 1
// baseline (4191.922 us; speedup 1.0000x reference)
//
#include <hip/hip_runtime.h>

// SpMiddleAlinPreFramesNoDownsampleXYMultiStep — round 1: correctness-first fp32
// tiled gather-conv implementation.
//
// Structure per frame t (T=3):
//   subm1(16->32), subm2(32->32), spcv1(32->64,+a0), subm3/4/5(64->64),
//   spcv2(64->64,+a1), subm6/7/8(64->64), spcv3(K=3,64->64,+a2),
//   scatter to dense (256,320,320), then a0/a1/a2 updated from
//   mean-of-adapt(x3/x7/x11) (a 64-vector each; second matmul is linear so
//   it is applied to the row-mean of relu(bn_ad(s@w_ad1))).

#define BN_EPS_F 1e-3f

// ---------------------------------------------------------------------------
// gather-conv + BN + ReLU (+ optional per-channel avec added pre-BN)
// out[m, co] = relu(bn( sum_k sum_ci f[idx[m,k], ci] * w[k,ci,co] (+ avec[co]) ))
// Block: 64 output rows x Co cols. threads = (Co/4, 16); 4x4 register tile.
// ---------------------------------------------------------------------------
template<int Ci, int Co, int K>
__global__ __launch_bounds__(16*(Co/4))
void gconv_bn_relu(const float* __restrict__ fin,
                   const int*   __restrict__ idx,
                   const float* __restrict__ w,     // [K, Ci, Co]
                   const float* __restrict__ bnp,   // [4, Co] g,b,m,v
                   const float* __restrict__ avec,  // [Co] or nullptr
                   float* __restrict__ fout,
                   int M)
{
    constexpr int TX  = Co / 4;
    constexpr int NT  = 16 * TX;
    constexpr int F4R = Ci / 4;          // float4 per gathered row
    __shared__ float fT[Ci][64];         // transposed gathered features
    __shared__ float wsh[Ci * Co];       // weight slice for current k

    const int tx  = threadIdx.x;         // 0..TX-1 (col groups)
    const int ty  = threadIdx.y;         // 0..15   (row groups)
    const int tid = ty * TX + tx;
    const int m0  = blockIdx.x * 64;

    float acc[4][4] = {};

    for (int k = 0; k < K; ++k) {
        __syncthreads();
        // stage weights for this k (coalesced float4)
        for (int i = tid * 4; i < Ci * Co; i += NT * 4)
            *(float4*)&wsh[i] = *(const float4*)&w[(size_t)k * Ci * Co + i];
        // gather 64 rows x Ci features, store transposed
        for (int i = tid; i < 64 * F4R; i += NT) {
            int r = i / F4R;
            int q = i - r * F4R;
            int m = m0 + r;
            int n = (m < M) ? idx[(size_t)m * K + k] : -1;
            float4 v = make_float4(0.f, 0.f, 0.f, 0.f);
            if (n >= 0) v = *(const float4*)&fin[(size_t)n * Ci + q * 4];
            fT[q*4+0][r] = v.x; fT[q*4+1][r] = v.y;
            fT[q*4+2][r] = v.z; fT[q*4+3][r] = v.w;
        }
        __syncthreads();

        #pragma unroll 8
        for (int ci = 0; ci < Ci; ++ci) {
            float4 fv = *(const float4*)&fT[ci][4 * ty];
            float4 wv = *(const float4*)&wsh[ci * Co + 4 * tx];
            float fr[4] = {fv.x, fv.y, fv.z, fv.w};
            float wr[4] = {wv.x, wv.y, wv.z, wv.w};
            #pragma unroll
            for (int v2 = 0; v2 < 4; ++v2)
                #pragma unroll
                for (int u = 0; u < 4; ++u)
                    acc[v2][u] = fmaf(fr[v2], wr[u], acc[v2][u]);
        }
    }

    // epilogue: avec (pre-BN), BN, ReLU, coalesced float4 store
    float scale[4], shift[4], av[4];
    #pragma unroll
    for (int u = 0; u < 4; ++u) {
        int c = 4 * tx + u;
        float g = bnp[c], b = bnp[Co + c], mu = bnp[2*Co + c], var = bnp[3*Co + c];
        float s = g * rsqrtf(var + BN_EPS_F);
        scale[u] = s;
        shift[u] = b - mu * s;
        av[u] = avec ? avec[c] : 0.f;
    }
    #pragma unroll
    for (int v2 = 0; v2 < 4; ++v2) {
        int m = m0 + 4 * ty + v2;
        if (m < M) {
            float4 o;
            float vals[4];
            #pragma unroll
            for (int u = 0; u < 4; ++u) {
                float x = acc[v2][u] + av[u];
                vals[u] = fmaxf(fmaf(x, scale[u], shift[u]), 0.f);
            }
            o.x = vals[0]; o.y = vals[1]; o.z = vals[2]; o.w = vals[3];
            *(float4*)&fout[(size_t)m * Co + 4 * tx] = o;
        }
    }
}

// ---------------------------------------------------------------------------
// adapt partial: hsum[c] += sum_rows relu(bn_ad(s[r,:] @ w_ad1[:,c]))
// ---------------------------------------------------------------------------
__global__ __launch_bounds__(64)
void adapt_partial(const float* __restrict__ s, const float* __restrict__ w_ad1,
                   const float* __restrict__ bn_ad, float* __restrict__ hsum, int M)
{
    __shared__ float wl[64 * 64];
    const int c = threadIdx.x;
    for (int i = c; i < 64 * 64; i += 64) wl[i] = w_ad1[i];
    float g = bn_ad[c], b = bn_ad[64 + c], mu = bn_ad[128 + c], var = bn_ad[192 + c];
    float sc = g * rsqrtf(var + BN_EPS_F);
    float sh = b - mu * sc;
    __syncthreads();

    float hacc = 0.f;
    int r0 = blockIdx.x * 64;
    int r1 = min(r0 + 64, M);
    for (int r = r0; r < r1; ++r) {
        float acc = 0.f;
        #pragma unroll
        for (int i4 = 0; i4 < 16; ++i4) {
            float4 sv = *(const float4*)&s[(size_t)r * 64 + i4 * 4];
            acc = fmaf(sv.x, wl[(i4*4+0)*64 + c], acc);
            acc = fmaf(sv.y, wl[(i4*4+1)*64 + c], acc);
            acc = fmaf(sv.z, wl[(i4*4+2)*64 + c], acc);
            acc = fmaf(sv.w, wl[(i4*4+3)*64 + c], acc);
        }
        hacc += fmaxf(fmaf(acc, sc, sh), 0.f);
    }
    atomicAdd(&hsum[c], hacc);
}

// a[c] = ((hsum/M) @ w_ad2)[c] / 10
__global__ __launch_bounds__(64)
void adapt_finalize(const float* __restrict__ hsum, const float* __restrict__ w_ad2,
                    float* __restrict__ a, float invM)
{
    const int c = threadIdx.x;
    float acc = 0.f;
    #pragma unroll 8
    for (int j = 0; j < 64; ++j) acc = fmaf(hsum[j], w_ad2[j * 64 + c], acc);
    a[c] = (acc * invM) * 0.1f;
}

// scatter x11 into dense output slice: out[(c*4+z)*320*320 + y*320 + x] = x11[m,c]
__global__ __launch_bounds__(64)
void scatter_out(const float* __restrict__ x11, const int* __restrict__ coords,
                 float* __restrict__ out)
{
    const int m = blockIdx.x;
    const int c = threadIdx.x;
    int z = coords[m * 3 + 0], y = coords[m * 3 + 1], x = coords[m * 3 + 2];
    out[(size_t)(c * 4 + z) * (320 * 320) + y * 320 + x] = x11[(size_t)m * 64 + c];
}

// ---------------------------------------------------------------------------
extern "C" void kernel_launch(void* const* d_in, const int* in_sizes, int n_in,
                              void* d_out, int out_size, void* d_ws, size_t ws_size,
                              hipStream_t stream)
{
    const float* vf      = (const float*)d_in[0];
    const float* w_subm1 = (const float*)d_in[1];
    const float* w_subm2 = (const float*)d_in[2];
    const float* w_spcv1 = (const float*)d_in[3];
    const float* w_subm3 = (const float*)d_in[4];
    const float* w_subm4 = (const float*)d_in[5];
    const float* w_subm5 = (const float*)d_in[6];
    const float* w_spcv2 = (const float*)d_in[7];
    const float* w_subm6 = (const float*)d_in[8];
    const float* w_subm7 = (const float*)d_in[9];
    const float* w_subm8 = (const float*)d_in[10];
    const float* w_spcv3 = (const float*)d_in[11];
    const float* w_ad1   = (const float*)d_in[12];
    const float* w_ad2   = (const float*)d_in[13];
    const float* bn32    = (const float*)d_in[14];  // [2,4,32]
    const float* bn64    = (const float*)d_in[15];  // [9,4,64]
    const float* bn_ad   = (const float*)d_in[16];  // [4,64]
    const int* nbr0    = (const int*)d_in[17];
    const int* idx1    = (const int*)d_in[18];
    const int* nbr1    = (const int*)d_in[19];
    const int* idx2    = (const int*)d_in[20];
    const int* nbr2    = (const int*)d_in[21];
    const int* idx3    = (const int*)d_in[22];
    const int* coords3 = (const int*)d_in[23];

    const int M0 = in_sizes[0]  / (3 * 16);
    const int M1 = in_sizes[18] / 27;
    const int M2 = in_sizes[20] / 27;
    const int M3 = in_sizes[22] / 3;

    // workspace layout (floats, 256B-aligned chunks)
    float* wsf = (float*)d_ws;
    size_t off = 0;
    auto alloc = [&](size_t n) {
        float* p = wsf + off;
        off += (n + 63) & ~(size_t)63;
        return p;
    };
    float* buf0a = alloc((size_t)M0 * 32);
    float* buf0b = alloc((size_t)M0 * 32);
    float* x3    = alloc((size_t)M1 * 64);
    float* buf1a = alloc((size_t)M1 * 64);
    float* buf1b = alloc((size_t)M1 * 64);
    float* x7    = alloc((size_t)M2 * 64);
    float* buf2a = alloc((size_t)M2 * 64);
    float* buf2b = alloc((size_t)M2 * 64);
    float* x11   = alloc((size_t)M3 * 64);
    float* av    = alloc(192);   // a0,a1,a2 (64 each)
    float* hs    = alloc(192);   // hsum0,1,2
    (void)ws_size; (void)n_in;

    // output must be all-zero outside scattered voxels (buffer may be poisoned)
    hipMemsetAsync(d_out, 0, (size_t)out_size * sizeof(float), stream);

    const dim3 blk32(8, 16);    // Co=32 -> 128 threads
    const dim3 blk64(16, 16);   // Co=64 -> 256 threads
    const int g0 = (M0 + 63) / 64;
    const int g1 = (M1 + 63) / 64;
    const int g2 = (M2 + 63) / 64;
    const int g3 = (M3 + 63) / 64;

    for (int t = 0; t < 3; ++t) {
        const float* vft = vf + (size_t)t * M0 * 16;
        const float* a0 = (t == 0) ? nullptr : av + 0;
        const float* a1 = (t == 0) ? nullptr : av + 64;
        const float* a2 = (t == 0) ? nullptr : av + 128;

        gconv_bn_relu<16,32,27><<<g0, blk32, 0, stream>>>(vft,   nbr0, w_subm1, bn32 + 0,   nullptr, buf0a, M0);
        gconv_bn_relu<32,32,27><<<g0, blk32, 0, stream>>>(buf0a, nbr0, w_subm2, bn32 + 128, nullptr, buf0b, M0);
        gconv_bn_relu<32,64,27><<<g1, blk64, 0, stream>>>(buf0b, idx1, w_spcv1, bn64 + 0,   a0,      x3,    M1);
        gconv_bn_relu<64,64,27><<<g1, blk64, 0, stream>>>(x3,    nbr1, w_subm3, bn64 + 256, nullptr, buf1a, M1);
        gconv_bn_relu<64,64,27><<<g1, blk64, 0, stream>>>(buf1a, nbr1, w_subm4, bn64 + 512, nullptr, buf1b, M1);
        gconv_bn_relu<64,64,27><<<g1, blk64, 0, stream>>>(buf1b, nbr1, w_subm5, bn64 + 768, nullptr, buf1a, M1);
        gconv_bn_relu<64,64,27><<<g2, blk64, 0, stream>>>(buf1a, idx2, w_spcv2, bn64 + 1024, a1,     x7,    M2);
        gconv_bn_relu<64,64,27><<<g2, blk64, 0, stream>>>(x7,    nbr2, w_subm6, bn64 + 1280, nullptr, buf2a, M2);
        gconv_bn_relu<64,64,27><<<g2, blk64, 0, stream>>>(buf2a, nbr2, w_subm7, bn64 + 1536, nullptr, buf2b, M2);
        gconv_bn_relu<64,64,27><<<g2, blk64, 0, stream>>>(buf2b, nbr2, w_subm8, bn64 + 1792, nullptr, buf2a, M2);
        gconv_bn_relu<64,64,3><<<g3,  blk64, 0, stream>>>(buf2a, idx3, w_spcv3, bn64 + 2048, a2,     x11,   M3);

        scatter_out<<<M3, 64, 0, stream>>>(x11, coords3,
                                           (float*)d_out + (size_t)t * 256 * 320 * 320);

        if (t < 2) {  // last frame's adapt is unused by the output
            hipMemsetAsync(hs, 0, 192 * sizeof(float), stream);
            adapt_partial<<<g1, 64, 0, stream>>>(x3,  w_ad1, bn_ad, hs + 0,   M1);
            adapt_partial<<<g2, 64, 0, stream>>>(x7,  w_ad1, bn_ad, hs + 64,  M2);
            adapt_partial<<<g3, 64, 0, stream>>>(x11, w_ad1, bn_ad, hs + 128, M3);
            adapt_finalize<<<1, 64, 0, stream>>>(hs + 0,   w_ad2, av + 0,   1.f / M1);
            adapt_finalize<<<1, 64, 0, stream>>>(hs + 64,  w_ad2, av + 64,  1.f / M2);
            adapt_finalize<<<1, 64, 0, stream>>>(hs + 128, w_ad2, av + 128, 1.f / M3);
        }
    }
}

// Round 2
// 1363.406 us; speedup vs baseline: 3.0746x; 3.0746x over previous
//
#include <hip/hip_runtime.h>

// Round 2: f16 MFMA gather-convs (16x16x32), f16 intermediate features,
// weights pre-transposed to [K][Co][Ci] f16, custom zero-fill for d_out.

typedef _Float16 f16;
typedef _Float16 f16x8 __attribute__((ext_vector_type(8)));
typedef _Float16 f16x4 __attribute__((ext_vector_type(4)));
typedef float    f32x4 __attribute__((ext_vector_type(4)));

#define BN_EPS_F 1e-3f

// ---------------------------------------------------------------------------
__global__ __launch_bounds__(256)
void fill_zero(float4* __restrict__ p, long n4)
{
    long i  = blockIdx.x * 256L + threadIdx.x;
    long st = gridDim.x * 256L;
    float4 z = make_float4(0.f, 0.f, 0.f, 0.f);
    for (; i < n4; i += st) p[i] = z;
}

// w [K][Ci][Co] f32  ->  wT [K][Co][Ci] f16
__global__ __launch_bounds__(256)
void wxform(const float* __restrict__ w, f16* __restrict__ wT, int K, int Ci, int Co)
{
    int i = blockIdx.x * 256 + threadIdx.x;
    int total = K * Ci * Co;
    if (i >= total) return;
    int k  = i / (Ci * Co);
    int r  = i - k * (Ci * Co);
    int ci = r / Co;
    int co = r - ci * Co;
    wT[((size_t)k * Co + co) * Ci + ci] = (f16)w[i];
}

// ---------------------------------------------------------------------------
// MFMA gather-conv + BN + ReLU (+avec pre-BN).
// Block: 64 output rows, 512 threads = 8 waves in 2 groups; group g handles
// tap half g, each group stages its own A (gathered rows) and B (weight
// slice) LDS tiles; fp32 cross-group reduce at the end.
// Fragment layout (learn_hip verified): A/B lane l: row/col=l&15, k=(l>>4)*8
// contiguous 8; C/D: col=lane&15, row=(lane>>4)*4+reg.
// ---------------------------------------------------------------------------
template<int Ci, int Co, int K>
__global__ __launch_bounds__(512)
void gconv_mfma(const f16* __restrict__ fin, const int* __restrict__ idx,
                const f16* __restrict__ wT,   // [K][Co][Ci]
                const float* __restrict__ bnp,
                const float* __restrict__ avec,
                f16* __restrict__ fout, int M)
{
    constexpr int CiP = Ci + 8;      // padded LDS row stride (f16) -> 2-way banks
    constexpr int cpr = Ci / 8;      // 16B chunks per row
    constexpr int NF  = Co / 16;     // column fragments
    constexpr int KK  = Ci / 32;     // MFMA k-steps per tap
    constexpr int KH  = (K + 1) / 2; // taps in group 0

    __shared__ f16 Ab[2][64 * CiP];
    __shared__ f16 Bb[2][Co * CiP];

    const int tid  = threadIdx.x;
    const int lane = tid & 63;
    const int wv   = tid >> 6;   // 0..7
    const int g    = wv >> 2;    // tap-half group
    const int wq   = wv & 3;     // wave in group -> 16-row slice
    const int gtid = tid & 255;
    const int m0   = blockIdx.x * 64;
    const int l15  = lane & 15;
    const int kg   = lane >> 4;

    f32x4 acc[NF];
    #pragma unroll
    for (int nf = 0; nf < NF; ++nf) acc[nf] = (f32x4){0.f, 0.f, 0.f, 0.f};

    for (int it = 0; it < KH; ++it) {
        const int  k   = (g == 0) ? it : (KH + it);
        const bool act = (g == 0) || (k < K);
        __syncthreads();   // protect previous iter's MFMA reads
        if (act) {
            // stage A: gather 64 rows x Ci f16
            for (int i = gtid; i < 64 * cpr; i += 256) {
                int r = i / cpr, q = i - r * cpr;
                int m = m0 + r;
                int n = (m < M) ? idx[(size_t)m * K + k] : -1;
                uint4 v = make_uint4(0u, 0u, 0u, 0u);
                if (n >= 0) v = *(const uint4*)&fin[(size_t)n * Ci + q * 8];
                *(uint4*)&Ab[g][r * CiP + q * 8] = v;
            }
            // stage B: weight slice [Co][Ci]
            for (int i = gtid; i < Co * cpr; i += 256) {
                int co = i / cpr, q = i - co * cpr;
                *(uint4*)&Bb[g][co * CiP + q * 8] =
                    *(const uint4*)&wT[((size_t)k * Co + co) * Ci + q * 8];
            }
        }
        __syncthreads();
        if (act) {
            #pragma unroll
            for (int kk = 0; kk < KK; ++kk) {
                f16x8 af = *(const f16x8*)&Ab[g][(wq * 16 + l15) * CiP + kk * 32 + kg * 8];
                #pragma unroll
                for (int nf = 0; nf < NF; ++nf) {
                    f16x8 bf = *(const f16x8*)&Bb[g][(nf * 16 + l15) * CiP + kk * 32 + kg * 8];
                    acc[nf] = __builtin_amdgcn_mfma_f32_16x16x32_f16(af, bf, acc[nf], 0, 0, 0);
                }
            }
        }
    }

    // cross-group reduce (group1 -> LDS fp32, group0 adds) + epilogue
    float* red = (float*)&Ab[0][0];   // 64*Co f32 fits in Ab region
    __syncthreads();
    if (g == 1) {
        #pragma unroll
        for (int nf = 0; nf < NF; ++nf)
            #pragma unroll
            for (int j = 0; j < 4; ++j)
                red[(wq * 16 + kg * 4 + j) * Co + nf * 16 + l15] = acc[nf][j];
    }
    __syncthreads();
    if (g == 0) {
        #pragma unroll
        for (int nf = 0; nf < NF; ++nf) {
            int c = nf * 16 + l15;
            float gg = bnp[c], bb = bnp[Co + c], mu = bnp[2 * Co + c], vv = bnp[3 * Co + c];
            float sc = gg * rsqrtf(vv + BN_EPS_F);
            float sh = bb - mu * sc;
            float av = avec ? avec[c] : 0.f;
            #pragma unroll
            for (int j = 0; j < 4; ++j) {
                int row = wq * 16 + kg * 4 + j;
                int m = m0 + row;
                if (m < M) {
                    float x = acc[nf][j] + red[row * Co + c] + av;
                    fout[(size_t)m * Co + c] = (f16)fmaxf(fmaf(x, sc, sh), 0.f);
                }
            }
        }
    }
}

// ---------------------------------------------------------------------------
// subm1: 16->32, fp32 vector math (tiny share of FLOPs), f16 output.
// ---------------------------------------------------------------------------
__global__ __launch_bounds__(128)
void gconv16_32(const float* __restrict__ fin, const int* __restrict__ idx,
                const float* __restrict__ w, const float* __restrict__ bnp,
                f16* __restrict__ fout, int M)
{
    __shared__ float fT[16][64];
    __shared__ float wsh[16 * 32];
    const int tx  = threadIdx.x;   // 0..7
    const int ty  = threadIdx.y;   // 0..15
    const int tid = ty * 8 + tx;
    const int m0  = blockIdx.x * 64;

    float acc[4][4] = {};

    for (int k = 0; k < 27; ++k) {
        __syncthreads();
        *(float4*)&wsh[tid * 4] = *(const float4*)&w[(size_t)k * 512 + tid * 4];
        for (int i = tid; i < 64 * 4; i += 128) {
            int r = i >> 2, q = i & 3;
            int m = m0 + r;
            int n = (m < M) ? idx[(size_t)m * 27 + k] : -1;
            float4 v = make_float4(0.f, 0.f, 0.f, 0.f);
            if (n >= 0) v = *(const float4*)&fin[(size_t)n * 16 + q * 4];
            fT[q*4+0][r] = v.x; fT[q*4+1][r] = v.y;
            fT[q*4+2][r] = v.z; fT[q*4+3][r] = v.w;
        }
        __syncthreads();
        #pragma unroll
        for (int ci = 0; ci < 16; ++ci) {
            float4 fv = *(const float4*)&fT[ci][4 * ty];
            float4 wv = *(const float4*)&wsh[ci * 32 + 4 * tx];
            float fr[4] = {fv.x, fv.y, fv.z, fv.w};
            float wr[4] = {wv.x, wv.y, wv.z, wv.w};
            #pragma unroll
            for (int a = 0; a < 4; ++a)
                #pragma unroll
                for (int b = 0; b < 4; ++b)
                    acc[a][b] = fmaf(fr[a], wr[b], acc[a][b]);
        }
    }

    float scale[4], shift[4];
    #pragma unroll
    for (int u = 0; u < 4; ++u) {
        int c = 4 * tx + u;
        float gg = bnp[c], bb = bnp[32 + c], mu = bnp[64 + c], vv = bnp[96 + c];
        float s = gg * rsqrtf(vv + BN_EPS_F);
        scale[u] = s;
        shift[u] = bb - mu * s;
    }
    #pragma unroll
    for (int a = 0; a < 4; ++a) {
        int m = m0 + 4 * ty + a;
        if (m < M) {
            f16x4 o;
            #pragma unroll
            for (int u = 0; u < 4; ++u)
                o[u] = (f16)fmaxf(fmaf(acc[a][u], scale[u], shift[u]), 0.f);
            *(f16x4*)&fout[(size_t)m * 32 + 4 * tx] = o;
        }
    }
}

// ---------------------------------------------------------------------------
__global__ __launch_bounds__(64)
void adapt_partial(const f16* __restrict__ s, const float* __restrict__ w_ad1,
                   const float* __restrict__ bn_ad, float* __restrict__ hsum, int M)
{
    __shared__ float wl[64 * 64];
    const int c = threadIdx.x;
    for (int i = c; i < 64 * 64; i += 64) wl[i] = w_ad1[i];
    float gg = bn_ad[c], bb = bn_ad[64 + c], mu = bn_ad[128 + c], vv = bn_ad[192 + c];
    float sc = gg * rsqrtf(vv + BN_EPS_F);
    float sh = bb - mu * sc;
    __syncthreads();

    float hacc = 0.f;
    int r0 = blockIdx.x * 64;
    int r1 = min(r0 + 64, M);
    for (int r = r0; r < r1; ++r) {
        float acc = 0.f;
        #pragma unroll
        for (int i8 = 0; i8 < 8; ++i8) {
            f16x8 sv = *(const f16x8*)&s[(size_t)r * 64 + i8 * 8];
            #pragma unroll
            for (int e = 0; e < 8; ++e)
                acc = fmaf((float)sv[e], wl[(i8 * 8 + e) * 64 + c], acc);
        }
        hacc += fmaxf(fmaf(acc, sc, sh), 0.f);
    }
    atomicAdd(&hsum[c], hacc);
}

__global__ __launch_bounds__(64)
void adapt_finalize(const float* __restrict__ hsum, const float* __restrict__ w_ad2,
                    float* __restrict__ a, float invM)
{
    const int c = threadIdx.x;
    float acc = 0.f;
    #pragma unroll 8
    for (int j = 0; j < 64; ++j) acc = fmaf(hsum[j], w_ad2[j * 64 + c], acc);
    a[c] = (acc * invM) * 0.1f;
}

__global__ __launch_bounds__(64)
void scatter_out(const f16* __restrict__ x11, const int* __restrict__ coords,
                 float* __restrict__ out)
{
    const int m = blockIdx.x;
    const int c = threadIdx.x;
    int z = coords[m * 3 + 0], y = coords[m * 3 + 1], x = coords[m * 3 + 2];
    out[(size_t)(c * 4 + z) * (320 * 320) + y * 320 + x] = (float)x11[(size_t)m * 64 + c];
}

// ---------------------------------------------------------------------------
extern "C" void kernel_launch(void* const* d_in, const int* in_sizes, int n_in,
                              void* d_out, int out_size, void* d_ws, size_t ws_size,
                              hipStream_t stream)
{
    const float* vf      = (const float*)d_in[0];
    const float* w_subm1 = (const float*)d_in[1];
    const float* w_subm2 = (const float*)d_in[2];
    const float* w_spcv1 = (const float*)d_in[3];
    const float* w_subm3 = (const float*)d_in[4];
    const float* w_subm4 = (const float*)d_in[5];
    const float* w_subm5 = (const float*)d_in[6];
    const float* w_spcv2 = (const float*)d_in[7];
    const float* w_subm6 = (const float*)d_in[8];
    const float* w_subm7 = (const float*)d_in[9];
    const float* w_subm8 = (const float*)d_in[10];
    const float* w_spcv3 = (const float*)d_in[11];
    const float* w_ad1   = (const float*)d_in[12];
    const float* w_ad2   = (const float*)d_in[13];
    const float* bn32    = (const float*)d_in[14];
    const float* bn64    = (const float*)d_in[15];
    const float* bn_ad   = (const float*)d_in[16];
    const int* nbr0    = (const int*)d_in[17];
    const int* idx1    = (const int*)d_in[18];
    const int* nbr1    = (const int*)d_in[19];
    const int* idx2    = (const int*)d_in[20];
    const int* nbr2    = (const int*)d_in[21];
    const int* idx3    = (const int*)d_in[22];
    const int* coords3 = (const int*)d_in[23];

    const int M0 = in_sizes[0]  / (3 * 16);
    const int M1 = in_sizes[18] / 27;
    const int M2 = in_sizes[20] / 27;
    const int M3 = in_sizes[22] / 3;

    // byte-addressed workspace, 256B aligned chunks
    char* base = (char*)d_ws;
    size_t off = 0;
    auto alloc = [&](size_t bytes) -> void* {
        void* p = base + off;
        off = (off + bytes + 255) & ~(size_t)255;
        return p;
    };
    f16* wt_subm2 = (f16*)alloc((size_t)27 * 32 * 32 * 2);
    f16* wt_spcv1 = (f16*)alloc((size_t)27 * 32 * 64 * 2);
    f16* wt_subm3 = (f16*)alloc((size_t)27 * 64 * 64 * 2);
    f16* wt_subm4 = (f16*)alloc((size_t)27 * 64 * 64 * 2);
    f16* wt_subm5 = (f16*)alloc((size_t)27 * 64 * 64 * 2);
    f16* wt_spcv2 = (f16*)alloc((size_t)27 * 64 * 64 * 2);
    f16* wt_subm6 = (f16*)alloc((size_t)27 * 64 * 64 * 2);
    f16* wt_subm7 = (f16*)alloc((size_t)27 * 64 * 64 * 2);
    f16* wt_subm8 = (f16*)alloc((size_t)27 * 64 * 64 * 2);
    f16* wt_spcv3 = (f16*)alloc((size_t)3  * 64 * 64 * 2);
    f16* buf0a = (f16*)alloc((size_t)M0 * 32 * 2);
    f16* buf0b = (f16*)alloc((size_t)M0 * 32 * 2);
    f16* x3    = (f16*)alloc((size_t)M1 * 64 * 2);
    f16* buf1a = (f16*)alloc((size_t)M1 * 64 * 2);
    f16* buf1b = (f16*)alloc((size_t)M1 * 64 * 2);
    f16* x7    = (f16*)alloc((size_t)M2 * 64 * 2);
    f16* buf2a = (f16*)alloc((size_t)M2 * 64 * 2);
    f16* buf2b = (f16*)alloc((size_t)M2 * 64 * 2);
    f16* x11   = (f16*)alloc((size_t)M3 * 64 * 2);
    float* av  = (float*)alloc(192 * 4);
    float* hs  = (float*)alloc(192 * 4);
    (void)ws_size; (void)n_in;

    // weight transforms (once per launch)
    auto wx = [&](const float* w, f16* wt, int K, int Ci, int Co) {
        int total = K * Ci * Co;
        wxform<<<(total + 255) / 256, 256, 0, stream>>>(w, wt, K, Ci, Co);
    };
    wx(w_subm2, wt_subm2, 27, 32, 32);
    wx(w_spcv1, wt_spcv1, 27, 32, 64);
    wx(w_subm3, wt_subm3, 27, 64, 64);
    wx(w_subm4, wt_subm4, 27, 64, 64);
    wx(w_subm5, wt_subm5, 27, 64, 64);
    wx(w_spcv2, wt_spcv2, 27, 64, 64);
    wx(w_subm6, wt_subm6, 27, 64, 64);
    wx(w_subm7, wt_subm7, 27, 64, 64);
    wx(w_subm8, wt_subm8, 27, 64, 64);
    wx(w_spcv3, wt_spcv3, 3, 64, 64);

    // zero the dense output (poisoned once before timing)
    fill_zero<<<2048, 256, 0, stream>>>((float4*)d_out, (long)out_size / 4);

    const int g0 = (M0 + 63) / 64;
    const int g1 = (M1 + 63) / 64;
    const int g2 = (M2 + 63) / 64;
    const int g3 = (M3 + 63) / 64;

    for (int t = 0; t < 3; ++t) {
        const float* vft = vf + (size_t)t * M0 * 16;
        const float* a0 = (t == 0) ? nullptr : av + 0;
        const float* a1 = (t == 0) ? nullptr : av + 64;
        const float* a2 = (t == 0) ? nullptr : av + 128;

        gconv16_32<<<g0, dim3(8, 16), 0, stream>>>(vft, nbr0, w_subm1, bn32, buf0a, M0);
        gconv_mfma<32,32,27><<<g0, 512, 0, stream>>>(buf0a, nbr0, wt_subm2, bn32 + 128,  nullptr, buf0b, M0);
        gconv_mfma<32,64,27><<<g1, 512, 0, stream>>>(buf0b, idx1, wt_spcv1, bn64 + 0,    a0,      x3,    M1);
        gconv_mfma<64,64,27><<<g1, 512, 0, stream>>>(x3,    nbr1, wt_subm3, bn64 + 256,  nullptr, buf1a, M1);
        gconv_mfma<64,64,27><<<g1, 512, 0, stream>>>(buf1a, nbr1, wt_subm4, bn64 + 512,  nullptr, buf1b, M1);
        gconv_mfma<64,64,27><<<g1, 512, 0, stream>>>(buf1b, nbr1, wt_subm5, bn64 + 768,  nullptr, buf1a, M1);
        gconv_mfma<64,64,27><<<g2, 512, 0, stream>>>(buf1a, idx2, wt_spcv2, bn64 + 1024, a1,      x7,    M2);
        gconv_mfma<64,64,27><<<g2, 512, 0, stream>>>(x7,    nbr2, wt_subm6, bn64 + 1280, nullptr, buf2a, M2);
        gconv_mfma<64,64,27><<<g2, 512, 0, stream>>>(buf2a, nbr2, wt_subm7, bn64 + 1536, nullptr, buf2b, M2);
        gconv_mfma<64,64,27><<<g2, 512, 0, stream>>>(buf2b, nbr2, wt_subm8, bn64 + 1792, nullptr, buf2a, M2);
        gconv_mfma<64,64,3><<<g3,  512, 0, stream>>>(buf2a, idx3, wt_spcv3, bn64 + 2048, a2,      x11,   M3);

        scatter_out<<<M3, 64, 0, stream>>>(x11, coords3,
                                           (float*)d_out + (size_t)t * 256 * 320 * 320);

        if (t < 2) {
            hipMemsetAsync(hs, 0, 192 * sizeof(float), stream);
            adapt_partial<<<g1, 64, 0, stream>>>(x3,  w_ad1, bn_ad, hs + 0,   M1);
            adapt_partial<<<g2, 64, 0, stream>>>(x7,  w_ad1, bn_ad, hs + 64,  M2);
            adapt_partial<<<g3, 64, 0, stream>>>(x11, w_ad1, bn_ad, hs + 128, M3);
            adapt_finalize<<<1, 64, 0, stream>>>(hs + 0,   w_ad2, av + 0,   1.f / M1);
            adapt_finalize<<<1, 64, 0, stream>>>(hs + 64,  w_ad2, av + 64,  1.f / M2);
            adapt_finalize<<<1, 64, 0, stream>>>(hs + 128, w_ad2, av + 128, 1.f / M3);
        }
    }
}